// Round 12
// baseline (231.054 us; speedup 1.0000x reference)
//
#include <hip/hip_runtime.h>
#include <stdint.h>

#define S_LEN 4096
#define DM 1024
#define NH 16

typedef __attribute__((ext_vector_type(8))) short short8;
typedef __attribute__((ext_vector_type(4))) short short4v;
typedef __attribute__((ext_vector_type(4))) float float4v;
typedef __attribute__((ext_vector_type(4))) unsigned short ushort4v;

typedef __attribute__((address_space(1))) const void* as1cvp;
typedef __attribute__((address_space(3))) void* as3vp;

#define MFMA16(a, b, c) __builtin_amdgcn_mfma_f32_16x16x32_bf16((a), (b), (c), 0, 0, 0)
#define MFMA16K16(a, b, c) __builtin_amdgcn_mfma_f32_16x16x16bf16_1k((a), (b), (c), 0, 0, 0)
#define GLOAD_LDS16(g, l) \
  __builtin_amdgcn_global_load_lds((as1cvp)(g), (as3vp)(l), 16, 0, 0)

__device__ __forceinline__ unsigned short f2bf(float f) {
  unsigned u = __float_as_uint(f);
  u += 0x7fffu + ((u >> 16) & 1u);
  return (unsigned short)(u >> 16);
}

__device__ __forceinline__ float exp2_hw(float x) {
  float r;
  asm("v_exp_f32 %0, %1" : "=v"(r) : "v"(x));
  return r;
}

// ---------------- cast fp32 -> bf16 into workspace ----------------
__global__ __launch_bounds__(256) void cast_all(
    const float* __restrict__ q, const float* __restrict__ k, const float* __restrict__ v,
    const float* __restrict__ wq, const float* __restrict__ wk, const float* __restrict__ wv,
    const float* __restrict__ wo, unsigned short* __restrict__ dst)
{
  const float* src; size_t off; int n;
  switch (blockIdx.y) {
    case 0: src = q;  off = 0u;        n = 4194304; break;
    case 1: src = k;  off = 4194304u;  n = 4194304; break;
    case 2: src = v;  off = 8388608u;  n = 4194304; break;
    case 3: src = wq; off = 12582912u; n = 1048576; break;
    case 4: src = wk; off = 13631488u; n = 1048576; break;
    case 5: src = wv; off = 14680064u; n = 1048576; break;
    default: src = wo; off = 15728640u; n = 1048576; break;
  }
  int nv = n >> 2;
  for (int i = blockIdx.x * blockDim.x + threadIdx.x; i < nv; i += gridDim.x * blockDim.x) {
    float4v val = ((const float4v*)src)[i];
    ushort4v o;
    o.x = f2bf(val.x); o.y = f2bf(val.y); o.z = f2bf(val.z); o.w = f2bf(val.w);
    ((ushort4v*)(dst + off))[i] = o;
  }
}

// ---------------- 128x128 bt-GEMM tile (m97 structure) ----------------
// MODE 0: bf16 row-major out; MODE 1: f32 row-major out; MODE 2: bf16 TRANSPOSED out [N][4096]
template<int MODE>
__device__ __forceinline__ void gemm128(
    const unsigned short* __restrict__ A, const unsigned short* __restrict__ Bw,
    unsigned short* Cb, float* Cf, const float* __restrict__ bias, float alpha,
    unsigned short* As, unsigned short* Bs)
{
  const int K = 1024, N = 1024;
  int bm = blockIdx.x, bn = blockIdx.y;
  int t = threadIdx.x, lane = t & 63, w = t >> 6;
  int l15 = lane & 15, l4 = lane >> 4;
  int wr = w >> 1, wc = w & 1;

  float4v acc[4][4] = {};

  for (int kt = 0; kt < K / 32; ++kt) {
#pragma unroll
    for (int i = 0; i < 2; ++i) {
      int ci = i * 256 + t;
      int r = ci >> 2, cb = ci & 3;
      GLOAD_LDS16(A + (size_t)(bm * 128 + r) * K + kt * 32 + cb * 8,
                  As + (size_t)(i * 256 + w * 64) * 8);
      GLOAD_LDS16(Bw + (size_t)(bn * 128 + r) * K + kt * 32 + cb * 8,
                  Bs + (size_t)(i * 256 + w * 64) * 8);
    }
    __syncthreads();
    short8 af[4], bfr[4];
#pragma unroll
    for (int mf = 0; mf < 4; ++mf)
      af[mf] = *(const short8*)&As[(wr * 64 + mf * 16 + l15) * 32 + l4 * 8];
#pragma unroll
    for (int nf = 0; nf < 4; ++nf)
      bfr[nf] = *(const short8*)&Bs[(wc * 64 + nf * 16 + l15) * 32 + l4 * 8];
#pragma unroll
    for (int mf = 0; mf < 4; ++mf)
#pragma unroll
      for (int nf = 0; nf < 4; ++nf)
        acc[mf][nf] = MFMA16(af[mf], bfr[nf], acc[mf][nf]);
    __syncthreads();
  }

#pragma unroll
  for (int mf = 0; mf < 4; ++mf)
#pragma unroll
    for (int nf = 0; nf < 4; ++nf) {
      int col = bn * 128 + wc * 64 + nf * 16 + l15;
      float bv = bias[col];
#pragma unroll
      for (int j = 0; j < 4; ++j) {
        int row = bm * 128 + wr * 64 + mf * 16 + l4 * 4 + j;
        float val = (acc[mf][nf][j] + bv) * alpha;
        if (MODE == 1)      Cf[(size_t)row * N + col] = val;
        else if (MODE == 2) Cb[(size_t)col * S_LEN + row] = f2bf(val);  // transposed
        else                Cb[(size_t)row * N + col] = f2bf(val);
      }
    }
}

__global__ __launch_bounds__(256) void proj_qkv(
    const unsigned short* xq, const unsigned short* xk, const unsigned short* xv,
    const unsigned short* wq, const unsigned short* wk, const unsigned short* wv,
    unsigned short* Qp, unsigned short* Kp, unsigned short* Vt,
    const float* bq, const float* bk, const float* bv)
{
  __shared__ unsigned short As[128 * 32], Bs[128 * 32];
  switch (blockIdx.z) {
    // Q scale = (1/sqrt(64)) * log2(e): softmax runs in exp2 domain
    case 0:  gemm128<0>(xq, wq, Qp, nullptr, bq, 0.1803368867f, As, Bs); break;
    case 1:  gemm128<0>(xk, wk, Kp, nullptr, bk, 1.0f,          As, Bs); break;
    default: gemm128<2>(xv, wv, Vt, nullptr, bv, 1.0f,          As, Bs); break; // V^T [1024][4096]
  }
}

__global__ __launch_bounds__(256) void proj_o(
    const unsigned short* ctx, const unsigned short* wo, float* out, const float* bo)
{
  __shared__ unsigned short As[128 * 32], Bs[128 * 32];
  gemm128<1>(ctx, wo, nullptr, out, bo, 1.0f, As, Bs);
}

// ---------------- fused flash attention ----------------
// 512 blocks (XCD-swizzled) x 512 threads (8 waves).
// Wave = 32 q-rows x 32 d-cols (qs = w>>1, dh = w&1): K b128-frags amortized over
// 2 q-row-blocks (mf), V b64-frags halved. 16 waves/CU.
// Online softmax with defer-max THR=11.5 (exp2 domain) -- the r10-PROVEN numerics
// (p <= 1 always; garbage-tolerant). l_run kept as per-lane partials (corr is
// row-uniform so partial-scaling is exact); reduced once at the end.
// PV via mfma 16x16x16 with in-register P (A-frag == QK^T C/D layout).
template<int BUF>
__device__ __forceinline__ void attn_tile(
    int kt,
    const unsigned short* kb0, const unsigned short* kb1,
    const int (&vAe)[4], const unsigned short* vbase,
    const unsigned short* kg, const unsigned short* vg,
    unsigned short* kls, unsigned short* vls,
    const short8 (&qf)[2][2], float4v (&acc_o)[2][2],
    float (&m_run)[2], float (&l_run)[2], int l4)
{
  if (kt + 1 < 64) {   // prefetch next tile into the other buffer
    GLOAD_LDS16(kg + (size_t)(kt + 1) * (64 * DM), kls + (1 - BUF) * 4096);
    GLOAD_LDS16(vg + (kt + 1) * 64, vls + (1 - BUF) * 4096);
  }

  // ---- QK^T (swapped: A = K rows, B = Q rows); K-frags shared across mf ----
  float4v sc[2][4];
#pragma unroll
  for (int nf = 0; nf < 4; ++nf) {
    short8 kf0 = *(const short8*)(kb0 + BUF * 4096 + nf * 1024);
    short8 kf1 = *(const short8*)(kb1 + BUF * 4096 + nf * 1024);
#pragma unroll
    for (int mf = 0; mf < 2; ++mf) {
      float4v z = {0.f, 0.f, 0.f, 0.f};
      z = MFMA16(kf0, qf[mf][0], z);
      sc[mf][nf] = MFMA16(kf1, qf[mf][1], z);
    }
  }

  // ---- online softmax per row-block (row q = mf*16 + l15), defer-max ----
  short4v pa[2][4];
#pragma unroll
  for (int mf = 0; mf < 2; ++mf) {
    float mx = fmaxf(fmaxf(fmaxf(sc[mf][0][0], sc[mf][0][1]), sc[mf][0][2]), sc[mf][0][3]);
#pragma unroll
    for (int nf = 1; nf < 4; ++nf)
      mx = fmaxf(fmaxf(fmaxf(fmaxf(mx, sc[mf][nf][0]), sc[mf][nf][1]), sc[mf][nf][2]), sc[mf][nf][3]);
    mx = fmaxf(mx, __shfl_xor(mx, 16));
    mx = fmaxf(mx, __shfl_xor(mx, 32));

    if (!__all(mx <= m_run[mf] + 11.5f)) {   // defer-max (11.5 = 8 nats in log2)
      float mnew = fmaxf(m_run[mf], mx);
      float corr = exp2_hw(m_run[mf] - mnew);
      m_run[mf] = mnew;
      l_run[mf] *= corr;                     // valid on per-lane partials (row-uniform corr)
#pragma unroll
      for (int j = 0; j < 4; ++j) {
        float cj = __shfl(corr, l4 * 4 + j);
#pragma unroll
        for (int i2 = 0; i2 < 2; ++i2) acc_o[mf][i2][j] *= cj;
      }
    }

    float ps = 0.f;
#pragma unroll
    for (int nf = 0; nf < 4; ++nf) {
      float p0 = exp2_hw(sc[mf][nf][0] - m_run[mf]);
      float p1 = exp2_hw(sc[mf][nf][1] - m_run[mf]);
      float p2 = exp2_hw(sc[mf][nf][2] - m_run[mf]);
      float p3 = exp2_hw(sc[mf][nf][3] - m_run[mf]);
      ps += (p0 + p1) + (p2 + p3);
      unsigned lo, hi;
      asm("v_cvt_pk_bf16_f32 %0, %1, %2" : "=v"(lo) : "v"(p0), "v"(p1));
      asm("v_cvt_pk_bf16_f32 %0, %1, %2" : "=v"(hi) : "v"(p2), "v"(p3));
      union { unsigned u[2]; short4v s; } pk;
      pk.u[0] = lo; pk.u[1] = hi;
      pa[mf][nf] = pk.s;
    }
    l_run[mf] += ps;   // per-lane partial (16 k-cols of row mf*16+l15)
  }

  // ---- PV: d-half only (2 d-blocks), V b64 frags shared across mf ----
#pragma unroll
  for (int i = 0; i < 2; ++i)
#pragma unroll
    for (int nf = 0; nf < 4; ++nf) {
      short4v vf = *(const short4v*)(vbase + vAe[nf] + BUF * 4096 + i * 1024);
      acc_o[0][i] = MFMA16K16(pa[0][nf], vf, acc_o[0][i]);
      acc_o[1][i] = MFMA16K16(pa[1][nf], vf, acc_o[1][i]);
    }

  __syncthreads();   // drains prefetch (vmcnt) + all waves done with buf[BUF]
}

__global__ __launch_bounds__(512) void attn_fused(
    const unsigned short* __restrict__ Qp, const unsigned short* __restrict__ Kp,
    const unsigned short* __restrict__ Vt, unsigned short* __restrict__ ctx)
{
  __shared__ unsigned short Ks[2][64 * 64];
  __shared__ unsigned short Vts[2][64 * 64];

  // bijective XCD swizzle: 512 blocks, 64 consecutive wg per XCD
  int bid = blockIdx.x;
  int wg = (bid & 7) * 64 + (bid >> 3);
  int h = wg >> 5, qt = wg & 31;

  int t = threadIdx.x, lane = t & 63, w = t >> 6;
  int l15 = lane & 15, l4 = lane >> 4;
  int qs = w >> 1, dh = w & 1;

  // Q fragments (pre-scaled by 0.125*log2e): rows qrow0 + mf*16 + l15
  short8 qf[2][2];
  int qrow0 = qt * 128 + qs * 32;
#pragma unroll
  for (int mf = 0; mf < 2; ++mf)
#pragma unroll
    for (int ks = 0; ks < 2; ++ks)
      qf[mf][ks] = *(const short8*)&Qp[(size_t)(qrow0 + mf * 16 + l15) * DM + h * 64 + ks * 32 + l4 * 8];

  float4v acc_o[2][2] = {};
  float m_run[2] = {-INFINITY, -INFINITY};
  float l_run[2] = {0.f, 0.f};

  // ---- precomputed per-lane LDS read addresses ----
  const int swz = l15 & 7;
  const unsigned short* kb0 = &Ks[0][l15 * 64 + ((l4) ^ swz) * 8];
  const unsigned short* kb1 = &Ks[0][l15 * 64 + ((4 + l4) ^ swz) * 8];
  // V b64 frags: row = dh*32 + i*16 + l15 (dh folded into vbase, i via +1024 imm)
  int vAe[4];
#pragma unroll
  for (int nf = 0; nf < 4; ++nf)
    vAe[nf] = l15 * 64 + (((2 * nf + (l4 >> 1)) ^ swz) * 8) + (l4 & 1) * 4;
  const unsigned short* vbase = &Vts[0][dh * 2048];

  // ---- staging addresses (512 threads: 1 K-load + 1 V-load each per tile) ----
  int sr = t >> 3, sp = t & 7;
  int slb = sp ^ (sr & 7);
  const unsigned short* kg = Kp + (size_t)sr * DM + h * 64 + slb * 8;
  const unsigned short* vg = Vt + (size_t)(h * 64 + sr) * S_LEN + slb * 8;
  unsigned short* kls = &Ks[0][t * 8];
  unsigned short* vls = &Vts[0][t * 8];

  GLOAD_LDS16(kg, kls);
  GLOAD_LDS16(vg, vls);
  __syncthreads();

  for (int kt = 0; kt < 64; kt += 2) {
    attn_tile<0>(kt,     kb0, kb1, vAe, vbase, kg, vg, kls, vls, qf, acc_o, m_run, l_run, l4);
    attn_tile<1>(kt + 1, kb0, kb1, vAe, vbase, kg, vg, kls, vls, qf, acc_o, m_run, l_run, l4);
  }

  // ---- final l reduction (once) + normalize + write ctx (bf16) ----
#pragma unroll
  for (int mf = 0; mf < 2; ++mf) {
    float lr = l_run[mf];
    lr += __shfl_xor(lr, 16);
    lr += __shfl_xor(lr, 32);
#pragma unroll
    for (int j = 0; j < 4; ++j) {
      float lj = __shfl(lr, l4 * 4 + j);   // lane l4*4+j has l15 == l4*4+j (full row sum)
      float inv = 1.0f / lj;
#pragma unroll
      for (int i = 0; i < 2; ++i) {
        int row = qrow0 + mf * 16 + l4 * 4 + j;
        int col = h * 64 + dh * 32 + i * 16 + l15;
        ctx[(size_t)row * DM + col] = f2bf(acc_o[mf][i][j] * inv);
      }
    }
  }
}

// ---------------- launcher ----------------
extern "C" void kernel_launch(void* const* d_in, const int* in_sizes, int n_in,
                              void* d_out, int out_size, void* d_ws, size_t ws_size,
                              hipStream_t stream) {
  const float* q  = (const float*)d_in[0];
  const float* k  = (const float*)d_in[1];
  const float* v  = (const float*)d_in[2];
  const float* wq = (const float*)d_in[3];
  const float* bq = (const float*)d_in[4];
  const float* wk = (const float*)d_in[5];
  const float* bk = (const float*)d_in[6];
  const float* wv = (const float*)d_in[7];
  const float* bv = (const float*)d_in[8];
  const float* wo = (const float*)d_in[9];
  const float* bo = (const float*)d_in[10];

  unsigned short* ws  = (unsigned short*)d_ws;
  unsigned short* qb  = ws;                 // 4M elems (reused as ctx later)
  unsigned short* kb  = ws + 4194304u;
  unsigned short* vb  = ws + 8388608u;
  unsigned short* wqb = ws + 12582912u;
  unsigned short* wkb = ws + 13631488u;
  unsigned short* wvb = ws + 14680064u;
  unsigned short* wob = ws + 15728640u;
  unsigned short* Qp  = ws + 16777216u;
  unsigned short* Kp  = ws + 20971520u;
  unsigned short* Vt  = ws + 25165824u;     // V^T [1024][4096]
  unsigned short* ctx = qb;                 // safe reuse: qb consumed by proj_qkv before attn
  float* out = (float*)d_out;

  cast_all<<<dim3(1024, 7), 256, 0, stream>>>(q, k, v, wq, wk, wv, wo, ws);
  proj_qkv<<<dim3(32, 8, 3), 256, 0, stream>>>(qb, kb, vb, wqb, wkb, wvb, Qp, Kp, Vt, bq, bk, bv);
  attn_fused<<<dim3(512), 512, 0, stream>>>(Qp, Kp, Vt, ctx);
  proj_o<<<dim3(32, 8), 256, 0, stream>>>(ctx, wob, out, bo);
}